// Round 6
// baseline (1256.680 us; speedup 1.0000x reference)
//
#include <hip/hip_runtime.h>

typedef __bf16 bf16_t;
typedef bf16_t bf16x4 __attribute__((ext_vector_type(4)));
typedef bf16_t bf16x8 __attribute__((ext_vector_type(8)));
typedef float floatx4 __attribute__((ext_vector_type(4)));

#define MFMA16(a, b, c) __builtin_amdgcn_mfma_f32_16x16x32_bf16(a, b, c, 0, 0, 0)

// r6: inputs fp32 (R5's NaN proves bf16 reads are wrong: no NaN path exists
// with sane inputs), OUTPUT fp32 (R3/R4's deterministic structure-independent
// 9.81e-2 = fp32 read of packed bf16 pairs). Workspace 98 MiB (r1/r2 OOB fix).

__device__ __forceinline__ bf16x4 cvt4(float4 f) {
  bf16x4 o;
  o[0] = (bf16_t)f.x; o[1] = (bf16_t)f.y; o[2] = (bf16_t)f.z; o[3] = (bf16_t)f.w;
  return o;
}

// ---------------------------------------------------------------------------
// K0: bias[h][i][j] = table[rel_index[i*256+j]*8 + h]  (fp32, 2 MiB)
// ---------------------------------------------------------------------------
__global__ __launch_bounds__(256) void k_bias(const int* __restrict__ rel_index,
                                              const float* __restrict__ table,
                                              float* __restrict__ bias) {
  int ij = blockIdx.x * 256 + threadIdx.x;      // 0..65535
  int idx = rel_index[ij];
#pragma unroll
  for (int h = 0; h < 8; ++h)
    bias[h * 65536 + ij] = table[idx * 8 + h];
}

// ---------------------------------------------------------------------------
// K1: QKV GEMM. M=32768 rows (region-partition gather), K=512, N=1536.
// fp32 inputs converted to bf16 during LDS staging. 128x128 tile, 4 waves.
// ---------------------------------------------------------------------------
#define LDAB 40  // padded LDS row stride (elements)

__global__ __launch_bounds__(256) void k_qkv(const float* __restrict__ x,
                                             const float* __restrict__ wqkv,
                                             const float* __restrict__ bqkv,
                                             bf16_t* __restrict__ q,
                                             bf16_t* __restrict__ k,
                                             bf16_t* __restrict__ v) {
  __shared__ __align__(16) bf16_t As[128 * LDAB];
  __shared__ __align__(16) bf16_t Bs[128 * LDAB];

  const int tid = threadIdx.x;
  const int m0 = blockIdx.x * 128;
  const int n0 = blockIdx.y * 128;

  // staging: 128 rows x 32 kcols fp32 per tile; 4 float4 loads per thread
  const float* aptr[4];
  const float* bptr[4];
#pragma unroll
  for (int i = 0; i < 4; ++i) {
    int id = tid + 256 * i;               // 0..1023
    int row = id >> 3;                    // 0..127
    int c4 = (id & 7) * 4;                // 0..28
    int r = m0 + row;
    int w = r >> 8, n = r & 255;
    int b = w >> 4, wh = (w >> 2) & 3, ww = w & 3;
    int rh = n >> 4, rw = n & 15;
    int l = wh * 1024 + rh * 64 + ww * 16 + rw;
    aptr[i] = x + (size_t)(b * 4096 + l) * 512 + c4;
    bptr[i] = wqkv + (size_t)(n0 + row) * 512 + c4;
  }

  const int lane = tid & 63, wid = tid >> 6;
  const int wm = (wid >> 1) * 64, wn = (wid & 1) * 64;
  const int lm = lane & 15, lq = lane >> 4;

  floatx4 acc[4][4] = {};

  for (int k0 = 0; k0 < 512; k0 += 32) {
#pragma unroll
    for (int i = 0; i < 4; ++i) {
      int id = tid + 256 * i;
      float4 av = *(const float4*)(aptr[i] + k0);
      float4 bv = *(const float4*)(bptr[i] + k0);
      *(bf16x4*)&As[(id >> 3) * LDAB + (id & 7) * 4] = cvt4(av);
      *(bf16x4*)&Bs[(id >> 3) * LDAB + (id & 7) * 4] = cvt4(bv);
    }
    __syncthreads();
    bf16x8 af[4], bfr[4];
#pragma unroll
    for (int s = 0; s < 4; ++s) {
      af[s]  = *(const bf16x8*)&As[(wm + s * 16 + lm) * LDAB + lq * 8];
      bfr[s] = *(const bf16x8*)&Bs[(wn + s * 16 + lm) * LDAB + lq * 8];
    }
#pragma unroll
    for (int ms = 0; ms < 4; ++ms)
#pragma unroll
      for (int ns = 0; ns < 4; ++ns)
        acc[ms][ns] = MFMA16(af[ms], bfr[ns], acc[ms][ns]);
    __syncthreads();
  }

  // epilogue: scatter into q/k/v (w,h,n,d), q scaled by 0.125
#pragma unroll
  for (int ms = 0; ms < 4; ++ms) {
#pragma unroll
    for (int ns = 0; ns < 4; ++ns) {
      int col = n0 + wn + ns * 16 + lm;       // 0..1535
      int s = col >> 9, rem = col & 511;
      int hh = rem >> 6, d = rem & 63;
      bf16_t* dst = (s == 0) ? q : (s == 1) ? k : v;
      float bc = bqkv[col];
      float scale = (s == 0) ? 0.125f : 1.0f;
#pragma unroll
      for (int r = 0; r < 4; ++r) {
        int row = m0 + wm + ms * 16 + lq * 4 + r;
        int w = row >> 8, n = row & 255;
        float val = (acc[ms][ns][r] + bc) * scale;
        dst[(size_t)((w * 8 + hh) * 256 + n) * 64 + d] = (bf16_t)val;
      }
    }
  }
}

// ---------------------------------------------------------------------------
// K2: one block per (w,h). Loads v[w][h] into LDS transposed, then iterates
// the 16 query tiles with a 3-slot S-ring: S -> conv+bias -> softmax -> P ->
// PV -> O written in place of v[w][h] (block-private region: race-free).
// ---------------------------------------------------------------------------
__global__ __launch_bounds__(256) void k_attn(const bf16_t* __restrict__ q,
                                              const bf16_t* __restrict__ k,
                                              bf16_t* __restrict__ v_io,
                                              const float* __restrict__ bias,
                                              const float* __restrict__ pe_w,
                                              const float* __restrict__ pe_b) {
  __shared__ float ring[3][16][256];                 // 48 KB
  __shared__ __align__(16) bf16_t vT[64][264];       // 33 KB  (vT[d][tok])
  __shared__ __align__(16) bf16_t Pt[16][264];       // 8.25 KB
  __shared__ float redA[4][16];
  __shared__ float redB[4][16];
  __shared__ float pws[15];

  const int bh = blockIdx.x;             // 0..1023 = w*8 + h
  const int h = bh & 7;
  const bf16_t* qb = q + (size_t)bh * 16384;
  const bf16_t* kb = k + (size_t)bh * 16384;
  bf16_t* vb = v_io + (size_t)bh * 16384;            // read v, later write O
  const float* bb = bias + (size_t)h * 65536;
  const int tid = threadIdx.x, lane = tid & 63, wid = tid >> 6;
  const int lm = lane & 15, lq = lane >> 4;

  if (tid < 15) pws[tid] = pe_w[h * 15 + tid];
  const float peb = pe_b[h];

  // stage v -> LDS transposed
#pragma unroll
  for (int it = 0; it < 8; ++it) {
    int id = tid + 256 * it;             // 0..2047
    int tok = id >> 3, d8 = (id & 7) * 8;
    bf16x8 vv = *(const bf16x8*)(vb + (size_t)tok * 64 + d8);
#pragma unroll
    for (int j = 0; j < 8; ++j) vT[d8 + j][tok] = vv[j];
  }

  // K fragments (this wave's 64 key columns), reused across all query tiles
  bf16x8 b0[4], b1[4];
#pragma unroll
  for (int ns = 0; ns < 4; ++ns) {
    int tk = wid * 64 + ns * 16 + lm;
    b0[ns] = *(const bf16x8*)(kb + (size_t)tk * 64 + lq * 8);
    b1[ns] = *(const bf16x8*)(kb + (size_t)tk * 64 + 32 + lq * 8);
  }

  auto computeS = [&](int ti2) {
    if (ti2 >= 16) return;               // block-uniform
    int slot = ti2 % 3;
    int tq = ti2 * 16 + lm;
    bf16x8 a0 = *(const bf16x8*)(qb + (size_t)tq * 64 + lq * 8);
    bf16x8 a1 = *(const bf16x8*)(qb + (size_t)tq * 64 + 32 + lq * 8);
#pragma unroll
    for (int ns = 0; ns < 4; ++ns) {
      floatx4 acc = {0.f, 0.f, 0.f, 0.f};
      acc = MFMA16(a0, b0[ns], acc);
      acc = MFMA16(a1, b1[ns], acc);
#pragma unroll
      for (int r = 0; r < 4; ++r)
        ring[slot][lq * 4 + r][wid * 64 + ns * 16 + lm] = acc[r];
    }
  };

  computeS(0);
  const int c = tid;                     // this thread's key column
  for (int ti = 0; ti < 16; ++ti) {
    computeS(ti + 1);
    __syncthreads();                     // S (and, first iter, vT) ready

    // conv(15-tap over query axis) + pe_b + rel-pos bias
    float logits[16];
#pragma unroll
    for (int r = 0; r < 16; ++r) {
      int R = ti * 16 + r;
      float acc = ring[(R >> 4) % 3][R & 15][c] + peb + bb[(size_t)R * 256 + c];
#pragma unroll
      for (int j = 0; j < 15; ++j) {
        int R2 = R + j - 7;
        if (R2 >= 0 && R2 < 256)
          acc += ring[(R2 >> 4) % 3][R2 & 15][c] * pws[j];
      }
      logits[r] = fminf(fmaxf(acc, -80.f), 80.f);
    }

    // block-wide row softmax
#pragma unroll
    for (int r = 0; r < 16; ++r) {
      float m = logits[r];
      for (int off = 32; off; off >>= 1) m = fmaxf(m, __shfl_xor(m, off));
      if (lane == 0) redA[wid][r] = m;
    }
    __syncthreads();
#pragma unroll
    for (int r = 0; r < 16; ++r) {
      float mx = fmaxf(fmaxf(redA[0][r], redA[1][r]), fmaxf(redA[2][r], redA[3][r]));
      float p = __expf(logits[r] - mx);
      logits[r] = p;
      float s = p;
      for (int off = 32; off; off >>= 1) s += __shfl_xor(s, off);
      if (lane == 0) redB[wid][r] = s;
    }
    __syncthreads();
#pragma unroll
    for (int r = 0; r < 16; ++r) {
      float inv = 1.0f / (redB[0][r] + redB[1][r] + redB[2][r] + redB[3][r]);
      Pt[r][c] = (bf16_t)(logits[r] * inv);
    }
    __syncthreads();                     // Pt ready (also fences ring reads)

    // PV: wave wid covers d in [wid*16, wid*16+16)
    const int d = wid * 16 + lm;
    floatx4 oacc = {0.f, 0.f, 0.f, 0.f};
#pragma unroll
    for (int kt = 0; kt < 8; ++kt) {
      bf16x8 a = *(const bf16x8*)&Pt[lm][kt * 32 + lq * 8];
      bf16x8 b = *(const bf16x8*)&vT[d][kt * 32 + lq * 8];
      oacc = MFMA16(a, b, oacc);
    }
#pragma unroll
    for (int r = 0; r < 4; ++r) {
      int tok = ti * 16 + lq * 4 + r;
      vb[(size_t)tok * 64 + d] = (bf16_t)oacc[r];   // O[w][h][tok][d], in place
    }
    __syncthreads();                     // Pt/vT reads done before next writes
  }
}

// ---------------------------------------------------------------------------
// K5: proj GEMM. M=32768, K=512 (A in O-layout [w][h][n][d]), N=512 fp32 W.
// region_reverse folded into the output row map. Output fp32.
// ---------------------------------------------------------------------------
__global__ __launch_bounds__(256) void k_proj(const bf16_t* __restrict__ A,
                                              const float* __restrict__ Wp,
                                              const float* __restrict__ bp,
                                              float* __restrict__ out) {
  __shared__ __align__(16) bf16_t As[128 * LDAB];
  __shared__ __align__(16) bf16_t Bs[128 * LDAB];

  const int tid = threadIdx.x;
  const int m0 = blockIdx.x * 128;
  const int n0 = blockIdx.y * 128;
  const int lane = tid & 63, wid = tid >> 6;
  const int wm = (wid >> 1) * 64, wn = (wid & 1) * 64;
  const int lm = lane & 15, lq = lane >> 4;

  // A base per thread: row -> (w, n); channel ch = k0 + (id&3)*8, addressed as
  // (w*8 + ch>>6)*16384 + n*64 + (ch&63)
  size_t abase[2];
#pragma unroll
  for (int i = 0; i < 2; ++i) {
    int id = tid + 256 * i;               // 0..511
    int r = m0 + (id >> 2);
    int w = r >> 8, n = r & 255;
    abase[i] = (size_t)w * 131072 + (size_t)n * 64 + (id & 3) * 8;
  }
  const float* bptr[4];
#pragma unroll
  for (int i = 0; i < 4; ++i) {
    int id = tid + 256 * i;               // 0..1023
    bptr[i] = Wp + (size_t)(n0 + (id >> 3)) * 512 + (id & 7) * 4;
  }

  floatx4 acc[4][4] = {};

  for (int k0 = 0; k0 < 512; k0 += 32) {
#pragma unroll
    for (int i = 0; i < 2; ++i) {
      int id = tid + 256 * i;
      // (id&3)*8 < 32 so ch>>6 == k0>>6 uniformly within the chunk
      bf16x8 av = *(const bf16x8*)(A + abase[i] + (k0 >> 6) * 16384 + (k0 & 63));
      *(bf16x8*)&As[(id >> 2) * LDAB + (id & 3) * 8] = av;
    }
#pragma unroll
    for (int i = 0; i < 4; ++i) {
      int id = tid + 256 * i;
      float4 bv = *(const float4*)(bptr[i] + k0);
      *(bf16x4*)&Bs[(id >> 3) * LDAB + (id & 7) * 4] = cvt4(bv);
    }
    __syncthreads();
    bf16x8 af[4], bfr[4];
#pragma unroll
    for (int s = 0; s < 4; ++s) {
      af[s]  = *(const bf16x8*)&As[(wm + s * 16 + lm) * LDAB + lq * 8];
      bfr[s] = *(const bf16x8*)&Bs[(wn + s * 16 + lm) * LDAB + lq * 8];
    }
#pragma unroll
    for (int ms = 0; ms < 4; ++ms)
#pragma unroll
      for (int ns = 0; ns < 4; ++ns)
        acc[ms][ns] = MFMA16(af[ms], bfr[ns], acc[ms][ns]);
    __syncthreads();
  }

#pragma unroll
  for (int ms = 0; ms < 4; ++ms) {
#pragma unroll
    for (int r = 0; r < 4; ++r) {
      int row = m0 + wm + ms * 16 + lq * 4 + r;
      int w = row >> 8, n = row & 255;
      int b = w >> 4, wh = (w >> 2) & 3, ww = w & 3;
      int rh = n >> 4, rw = n & 15;
      int l = wh * 1024 + rh * 64 + ww * 16 + rw;
      size_t obase = (size_t)(b * 4096 + l) * 512;
#pragma unroll
      for (int ns = 0; ns < 4; ++ns) {
        int col = n0 + wn + ns * 16 + lm;
        out[obase + col] = acc[ms][ns][r] + bp[col];   // fp32 output
      }
    }
  }
}

// ---------------------------------------------------------------------------
extern "C" void kernel_launch(void* const* d_in, const int* in_sizes, int n_in,
                              void* d_out, int out_size, void* d_ws, size_t ws_size,
                              hipStream_t stream) {
  const float* x     = (const float*)d_in[0];
  const float* qkvw  = (const float*)d_in[1];
  const float* qkvb  = (const float*)d_in[2];
  const float* projw = (const float*)d_in[3];
  const float* projb = (const float*)d_in[4];
  const float* rbt   = (const float*)d_in[5];
  const float* pew   = (const float*)d_in[6];
  const float* peb   = (const float*)d_in[7];
  const int*   ridx  = (const int*)d_in[8];
  float* out = (float*)d_out;

  // Workspace: 98 MiB total (r1/r2 failed on a 130 MiB layout reading OOB).
  char* ws = (char*)d_ws;
  float*  bias = (float*)ws;                                 //  2 MiB
  bf16_t* q    = (bf16_t*)(ws + (2u << 20));                 // 32 MiB
  bf16_t* k    = (bf16_t*)(ws + (2u << 20) + 33554432u);     // 32 MiB
  bf16_t* v_o  = (bf16_t*)(ws + (2u << 20) + 67108864u);     // 32 MiB (v, then O)

  k_bias<<<256, 256, 0, stream>>>(ridx, rbt, bias);
  k_qkv<<<dim3(256, 12), 256, 0, stream>>>(x, qkvw, qkvb, q, k, v_o);
  k_attn<<<1024, 256, 0, stream>>>(q, k, v_o, bias, pew, peb);
  k_proj<<<dim3(256, 4), 256, 0, stream>>>(v_o, projw, projb, out);
}

// Round 7
// 572.045 us; speedup vs baseline: 2.1968x; 2.1968x over previous
//
#include <hip/hip_runtime.h>

typedef __bf16 bf16_t;
typedef bf16_t bf16x4 __attribute__((ext_vector_type(4)));
typedef bf16_t bf16x8 __attribute__((ext_vector_type(8)));
typedef float floatx4 __attribute__((ext_vector_type(4)));

#define MFMA16(a, b, c) __builtin_amdgcn_mfma_f32_16x16x32_bf16(a, b, c, 0, 0, 0)

__device__ __forceinline__ bf16x4 cvt4(float4 f) {
  bf16x4 o;
  o[0] = (bf16_t)f.x; o[1] = (bf16_t)f.y; o[2] = (bf16_t)f.z; o[3] = (bf16_t)f.w;
  return o;
}

// ---------------------------------------------------------------------------
// K0: bias[h][i][j] = table[rel_index[i*256+j]*8 + h]  (fp32, 2 MiB)
// ---------------------------------------------------------------------------
__global__ __launch_bounds__(256) void k_bias(const int* __restrict__ rel_index,
                                              const float* __restrict__ table,
                                              float* __restrict__ bias) {
  int ij = blockIdx.x * 256 + threadIdx.x;
  int idx = rel_index[ij];
#pragma unroll
  for (int h = 0; h < 8; ++h)
    bias[h * 65536 + ij] = table[idx * 8 + h];
}

// ---------------------------------------------------------------------------
// K1: QKV GEMM (unchanged from r6, correct & ~100us). M=32768, K=512, N=1536.
// ---------------------------------------------------------------------------
#define LDAB 40

__global__ __launch_bounds__(256) void k_qkv(const float* __restrict__ x,
                                             const float* __restrict__ wqkv,
                                             const float* __restrict__ bqkv,
                                             bf16_t* __restrict__ q,
                                             bf16_t* __restrict__ k,
                                             bf16_t* __restrict__ v) {
  __shared__ __align__(16) bf16_t As[128 * LDAB];
  __shared__ __align__(16) bf16_t Bs[128 * LDAB];

  const int tid = threadIdx.x;
  const int m0 = blockIdx.x * 128;
  const int n0 = blockIdx.y * 128;

  const float* aptr[4];
  const float* bptr[4];
#pragma unroll
  for (int i = 0; i < 4; ++i) {
    int id = tid + 256 * i;
    int row = id >> 3;
    int c4 = (id & 7) * 4;
    int r = m0 + row;
    int w = r >> 8, n = r & 255;
    int b = w >> 4, wh = (w >> 2) & 3, ww = w & 3;
    int rh = n >> 4, rw = n & 15;
    int l = wh * 1024 + rh * 64 + ww * 16 + rw;
    aptr[i] = x + (size_t)(b * 4096 + l) * 512 + c4;
    bptr[i] = wqkv + (size_t)(n0 + row) * 512 + c4;
  }

  const int lane = tid & 63, wid = tid >> 6;
  const int wm = (wid >> 1) * 64, wn = (wid & 1) * 64;
  const int lm = lane & 15, lq = lane >> 4;

  floatx4 acc[4][4] = {};

  for (int k0 = 0; k0 < 512; k0 += 32) {
#pragma unroll
    for (int i = 0; i < 4; ++i) {
      int id = tid + 256 * i;
      float4 av = *(const float4*)(aptr[i] + k0);
      float4 bv = *(const float4*)(bptr[i] + k0);
      *(bf16x4*)&As[(id >> 3) * LDAB + (id & 7) * 4] = cvt4(av);
      *(bf16x4*)&Bs[(id >> 3) * LDAB + (id & 7) * 4] = cvt4(bv);
    }
    __syncthreads();
    bf16x8 af[4], bfr[4];
#pragma unroll
    for (int s = 0; s < 4; ++s) {
      af[s]  = *(const bf16x8*)&As[(wm + s * 16 + lm) * LDAB + lq * 8];
      bfr[s] = *(const bf16x8*)&Bs[(wn + s * 16 + lm) * LDAB + lq * 8];
    }
#pragma unroll
    for (int ms = 0; ms < 4; ++ms)
#pragma unroll
      for (int ns = 0; ns < 4; ++ns)
        acc[ms][ns] = MFMA16(af[ms], bfr[ns], acc[ms][ns]);
    __syncthreads();
  }

#pragma unroll
  for (int ms = 0; ms < 4; ++ms) {
#pragma unroll
    for (int ns = 0; ns < 4; ++ns) {
      int col = n0 + wn + ns * 16 + lm;
      int s = col >> 9, rem = col & 511;
      int hh = rem >> 6, d = rem & 63;
      bf16_t* dst = (s == 0) ? q : (s == 1) ? k : v;
      float bc = bqkv[col];
      float scale = (s == 0) ? 0.125f : 1.0f;
#pragma unroll
      for (int r = 0; r < 4; ++r) {
        int row = m0 + wm + ms * 16 + lq * 4 + r;
        int w = row >> 8, n = row & 255;
        float val = (acc[ms][ns][r] + bc) * scale;
        dst[(size_t)((w * 8 + hh) * 256 + n) * 64 + d] = (bf16_t)val;
      }
    }
  }
}

// ---------------------------------------------------------------------------
// K2 fast: one block per (w,h,ti). 16384 independent blocks, short chain.
// LDS: phase A vbuf[256][68] bf16 (34816 B) -> V frags to REGISTERS; region
// reused phase B as S[30][260] f32 (31200) + Pt[16][264] bf16 (8448).
// No-max softmax (logits clamped +-60; exp cannot overflow; values ~+-2).
// ---------------------------------------------------------------------------
__global__ __launch_bounds__(256) void k_attn_t(const bf16_t* __restrict__ q,
                                                const bf16_t* __restrict__ k,
                                                const bf16_t* __restrict__ v,
                                                bf16_t* __restrict__ o,
                                                const float* __restrict__ bias,
                                                const float* __restrict__ pe_w,
                                                const float* __restrict__ pe_b) {
  __shared__ __align__(16) char pool[39648];   // max(34816, 31200+8448)
  __shared__ float redB[4][16];
  __shared__ float pws[15];
  bf16_t* vbuf = (bf16_t*)pool;                // [256][68]
  float*  S    = (float*)pool;                 // [30][260]
  bf16_t* Pt   = (bf16_t*)(pool + 31200);      // [16][264]

  const int blk = blockIdx.x;                  // bh*16 + ti
  const int ti = blk & 15, bh = blk >> 4;
  const int h = bh & 7;
  const bf16_t* qb = q + (size_t)bh * 16384;
  const bf16_t* kb = k + (size_t)bh * 16384;
  const bf16_t* vb = v + (size_t)bh * 16384;
  const float* bb = bias + (size_t)h * 65536;
  const int tid = threadIdx.x, lane = tid & 63, wid = tid >> 6;
  const int lm = lane & 15, lq = lane >> 4;
  const int dcol = wid * 16 + lm;

  if (tid < 15) pws[tid] = pe_w[h * 15 + tid];
  const float peb = pe_b[h];

  // phase A: stage v (natural layout, pad 68) -> V B-frags to registers
#pragma unroll
  for (int it = 0; it < 8; ++it) {
    int id = tid + 256 * it;
    int tok = id >> 3, d8 = (id & 7) * 8;
    *(bf16x8*)&vbuf[tok * 68 + d8] = *(const bf16x8*)(vb + tok * 64 + d8);
  }
  __syncthreads();
  bf16x8 vf[8];                                // wave's d=dcol, all 256 k
#pragma unroll
  for (int kt = 0; kt < 8; ++kt)
#pragma unroll
    for (int j = 0; j < 8; ++j)
      vf[kt][j] = vbuf[(kt * 32 + lq * 8 + j) * 68 + dcol];
  __syncthreads();                             // vbuf dead; S region live

  // K fragments: this wave's 64 keys, reused across the 3 q-tiles
  bf16x8 b0[4], b1[4];
#pragma unroll
  for (int ns = 0; ns < 4; ++ns) {
    int tk = wid * 64 + ns * 16 + lm;
    b0[ns] = *(const bf16x8*)(kb + (size_t)tk * 64 + lq * 8);
    b1[ns] = *(const bf16x8*)(kb + (size_t)tk * 64 + 32 + lq * 8);
  }

  // zero-pad halo rows at window edges (conv zero-padding semantics)
  if (ti == 0)
    for (int r = 0; r < 7; ++r) S[r * 260 + tid] = 0.f;
  if (ti == 15)
    for (int r = 23; r < 30; ++r) S[r * 260 + tid] = 0.f;

  // S tiles ti-1..ti+1 -> S[30][260] (local row = R - ti*16 + 7)
#pragma unroll
  for (int t = 0; t < 3; ++t) {
    int qt = ti - 1 + t;
    if (qt < 0 || qt > 15) continue;           // block-uniform
    int tq = qt * 16 + lm;
    bf16x8 a0 = *(const bf16x8*)(qb + (size_t)tq * 64 + lq * 8);
    bf16x8 a1 = *(const bf16x8*)(qb + (size_t)tq * 64 + 32 + lq * 8);
#pragma unroll
    for (int ns = 0; ns < 4; ++ns) {
      floatx4 acc = {0.f, 0.f, 0.f, 0.f};
      acc = MFMA16(a0, b0[ns], acc);
      acc = MFMA16(a1, b1[ns], acc);
      int col = wid * 64 + ns * 16 + lm;
#pragma unroll
      for (int r = 0; r < 4; ++r) {
        int lr = (t - 1) * 16 + 7 + lq * 4 + r;
        if (lr >= 0 && lr < 30) S[lr * 260 + col] = acc[r];
      }
    }
  }
  __syncthreads();

  // conv + pe_b + bias -> exp (no max-sub) ; thread owns key column c
  const int c = tid;
  float p[16];
#pragma unroll
  for (int r = 0; r < 16; ++r) {
    float acc = S[(r + 7) * 260 + c] + peb + bb[(size_t)(ti * 16 + r) * 256 + c];
#pragma unroll
    for (int j = 0; j < 15; ++j)
      acc += S[(r + j) * 260 + c] * pws[j];
    p[r] = __expf(fminf(fmaxf(acc, -60.f), 60.f));
  }
#pragma unroll
  for (int r = 0; r < 16; ++r) {
    float s = p[r];
    for (int off = 32; off; off >>= 1) s += __shfl_xor(s, off);
    if (lane == 0) redB[wid][r] = s;
  }
  __syncthreads();
#pragma unroll
  for (int r = 0; r < 16; ++r) {
    float inv = 1.0f / (redB[0][r] + redB[1][r] + redB[2][r] + redB[3][r]);
    Pt[r * 264 + c] = (bf16_t)(p[r] * inv);
  }
  __syncthreads();

  // PV: A from Pt (LDS), B from registers
  floatx4 oacc = {0.f, 0.f, 0.f, 0.f};
#pragma unroll
  for (int kt = 0; kt < 8; ++kt) {
    bf16x8 a = *(const bf16x8*)&Pt[lm * 264 + kt * 32 + lq * 8];
    oacc = MFMA16(a, vf[kt], oacc);
  }
  bf16_t* ob = o + (size_t)bh * 16384;
#pragma unroll
  for (int r = 0; r < 4; ++r)
    ob[(size_t)(ti * 16 + lq * 4 + r) * 64 + dcol] = (bf16_t)oacc[r];
}

// ---------------------------------------------------------------------------
// K2 fallback (ws too small for separate O): per-(w,h) serial over 16 tiles,
// O in place of v (block-private slab). vf in regs, padded ring, no-max
// softmax, 3 barriers/tile. ~57 KB LDS -> 2 blocks/CU.
// ---------------------------------------------------------------------------
__global__ __launch_bounds__(256) void k_attn_s(const bf16_t* __restrict__ q,
                                                const bf16_t* __restrict__ k,
                                                bf16_t* __restrict__ v_io,
                                                const float* __restrict__ bias,
                                                const float* __restrict__ pe_w,
                                                const float* __restrict__ pe_b) {
  __shared__ __align__(16) char pool[58368];   // ring 3*16*260*4=49920 + Pt 8448
  __shared__ float redB[4][16];
  __shared__ float pws[15];
  bf16_t* vbuf = (bf16_t*)pool;                // phase A only (34816 < 49920)
  float*  ring = (float*)pool;                 // [3][16][260]
  bf16_t* Pt   = (bf16_t*)(pool + 49920);      // [16][264]

  const int bh = blockIdx.x;
  const int h = bh & 7;
  const bf16_t* qb = q + (size_t)bh * 16384;
  const bf16_t* kb = k + (size_t)bh * 16384;
  bf16_t* vb = v_io + (size_t)bh * 16384;
  const float* bb = bias + (size_t)h * 65536;
  const int tid = threadIdx.x, lane = tid & 63, wid = tid >> 6;
  const int lm = lane & 15, lq = lane >> 4;
  const int dcol = wid * 16 + lm;

  if (tid < 15) pws[tid] = pe_w[h * 15 + tid];
  const float peb = pe_b[h];

#pragma unroll
  for (int it = 0; it < 8; ++it) {
    int id = tid + 256 * it;
    int tok = id >> 3, d8 = (id & 7) * 8;
    *(bf16x8*)&vbuf[tok * 68 + d8] = *(const bf16x8*)(vb + tok * 64 + d8);
  }
  __syncthreads();
  bf16x8 vf[8];
#pragma unroll
  for (int kt = 0; kt < 8; ++kt)
#pragma unroll
    for (int j = 0; j < 8; ++j)
      vf[kt][j] = vbuf[(kt * 32 + lq * 8 + j) * 68 + dcol];
  __syncthreads();                             // vbuf dead; ring live

  bf16x8 b0[4], b1[4];
#pragma unroll
  for (int ns = 0; ns < 4; ++ns) {
    int tk = wid * 64 + ns * 16 + lm;
    b0[ns] = *(const bf16x8*)(kb + (size_t)tk * 64 + lq * 8);
    b1[ns] = *(const bf16x8*)(kb + (size_t)tk * 64 + 32 + lq * 8);
  }

  auto computeS = [&](int ti2) {
    if (ti2 >= 16) return;                     // block-uniform
    int slot = ti2 % 3;
    int tq = ti2 * 16 + lm;
    bf16x8 a0 = *(const bf16x8*)(qb + (size_t)tq * 64 + lq * 8);
    bf16x8 a1 = *(const bf16x8*)(qb + (size_t)tq * 64 + 32 + lq * 8);
#pragma unroll
    for (int ns = 0; ns < 4; ++ns) {
      floatx4 acc = {0.f, 0.f, 0.f, 0.f};
      acc = MFMA16(a0, b0[ns], acc);
      acc = MFMA16(a1, b1[ns], acc);
      int col = wid * 64 + ns * 16 + lm;
#pragma unroll
      for (int r = 0; r < 4; ++r)
        ring[(slot * 16 + lq * 4 + r) * 260 + col] = acc[r];
    }
  };

  computeS(0);
  const int c = tid;
  for (int ti = 0; ti < 16; ++ti) {
    computeS(ti + 1);
    __syncthreads();                           // A: ring ready, prev Pt consumed

    float p[16];
#pragma unroll
    for (int r = 0; r < 16; ++r) {
      int R = ti * 16 + r;
      float acc = ring[((R >> 4) % 3 * 16 + (R & 15)) * 260 + c] + peb +
                  bb[(size_t)R * 256 + c];
#pragma unroll
      for (int j = 0; j < 15; ++j) {
        int R2 = R + j - 7;
        if (R2 >= 0 && R2 < 256)
          acc += ring[((R2 >> 4) % 3 * 16 + (R2 & 15)) * 260 + c] * pws[j];
      }
      p[r] = __expf(fminf(fmaxf(acc, -60.f), 60.f));
    }
#pragma unroll
    for (int r = 0; r < 16; ++r) {
      float s = p[r];
      for (int off = 32; off; off >>= 1) s += __shfl_xor(s, off);
      if (lane == 0) redB[wid][r] = s;
    }
    __syncthreads();                           // B: sums ready, conv reads done
#pragma unroll
    for (int r = 0; r < 16; ++r) {
      float inv = 1.0f / (redB[0][r] + redB[1][r] + redB[2][r] + redB[3][r]);
      Pt[r * 264 + c] = (bf16_t)(p[r] * inv);
    }
    __syncthreads();                           // C: Pt ready

    floatx4 oacc = {0.f, 0.f, 0.f, 0.f};
#pragma unroll
    for (int kt = 0; kt < 8; ++kt) {
      bf16x8 a = *(const bf16x8*)&Pt[lm * 264 + kt * 32 + lq * 8];
      oacc = MFMA16(a, vf[kt], oacc);
    }
#pragma unroll
    for (int r = 0; r < 4; ++r)
      vb[(size_t)(ti * 16 + lq * 4 + r) * 64 + dcol] = (bf16_t)oacc[r];
  }
}

// ---------------------------------------------------------------------------
// K5: proj GEMM (unchanged). A in O-layout [w][h][n][d]; fp32 output.
// ---------------------------------------------------------------------------
__global__ __launch_bounds__(256) void k_proj(const bf16_t* __restrict__ A,
                                              const float* __restrict__ Wp,
                                              const float* __restrict__ bp,
                                              float* __restrict__ out) {
  __shared__ __align__(16) bf16_t As[128 * LDAB];
  __shared__ __align__(16) bf16_t Bs[128 * LDAB];

  const int tid = threadIdx.x;
  const int m0 = blockIdx.x * 128;
  const int n0 = blockIdx.y * 128;
  const int lane = tid & 63, wid = tid >> 6;
  const int wm = (wid >> 1) * 64, wn = (wid & 1) * 64;
  const int lm = lane & 15, lq = lane >> 4;

  size_t abase[2];
#pragma unroll
  for (int i = 0; i < 2; ++i) {
    int id = tid + 256 * i;
    int r = m0 + (id >> 2);
    int w = r >> 8, n = r & 255;
    abase[i] = (size_t)w * 131072 + (size_t)n * 64 + (id & 3) * 8;
  }
  const float* bptr[4];
#pragma unroll
  for (int i = 0; i < 4; ++i) {
    int id = tid + 256 * i;
    bptr[i] = Wp + (size_t)(n0 + (id >> 3)) * 512 + (id & 7) * 4;
  }

  floatx4 acc[4][4] = {};

  for (int k0 = 0; k0 < 512; k0 += 32) {
#pragma unroll
    for (int i = 0; i < 2; ++i) {
      int id = tid + 256 * i;
      bf16x8 av = *(const bf16x8*)(A + abase[i] + (k0 >> 6) * 16384 + (k0 & 63));
      *(bf16x8*)&As[(id >> 2) * LDAB + (id & 3) * 8] = av;
    }
#pragma unroll
    for (int i = 0; i < 4; ++i) {
      int id = tid + 256 * i;
      float4 bv = *(const float4*)(bptr[i] + k0);
      *(bf16x4*)&Bs[(id >> 3) * LDAB + (id & 7) * 4] = cvt4(bv);
    }
    __syncthreads();
    bf16x8 af[4], bfr[4];
#pragma unroll
    for (int s = 0; s < 4; ++s) {
      af[s]  = *(const bf16x8*)&As[(wm + s * 16 + lm) * LDAB + lq * 8];
      bfr[s] = *(const bf16x8*)&Bs[(wn + s * 16 + lm) * LDAB + lq * 8];
    }
#pragma unroll
    for (int ms = 0; ms < 4; ++ms)
#pragma unroll
      for (int ns = 0; ns < 4; ++ns)
        acc[ms][ns] = MFMA16(af[ms], bfr[ns], acc[ms][ns]);
    __syncthreads();
  }

#pragma unroll
  for (int ms = 0; ms < 4; ++ms) {
#pragma unroll
    for (int r = 0; r < 4; ++r) {
      int row = m0 + wm + ms * 16 + lq * 4 + r;
      int w = row >> 8, n = row & 255;
      int b = w >> 4, wh = (w >> 2) & 3, ww = w & 3;
      int rh = n >> 4, rw = n & 15;
      int l = wh * 1024 + rh * 64 + ww * 16 + rw;
      size_t obase = (size_t)(b * 4096 + l) * 512;
#pragma unroll
      for (int ns = 0; ns < 4; ++ns) {
        int col = n0 + wn + ns * 16 + lm;
        out[obase + col] = acc[ms][ns][r] + bp[col];
      }
    }
  }
}

// ---------------------------------------------------------------------------
extern "C" void kernel_launch(void* const* d_in, const int* in_sizes, int n_in,
                              void* d_out, int out_size, void* d_ws, size_t ws_size,
                              hipStream_t stream) {
  const float* x     = (const float*)d_in[0];
  const float* qkvw  = (const float*)d_in[1];
  const float* qkvb  = (const float*)d_in[2];
  const float* projw = (const float*)d_in[3];
  const float* projb = (const float*)d_in[4];
  const float* rbt   = (const float*)d_in[5];
  const float* pew   = (const float*)d_in[6];
  const float* peb   = (const float*)d_in[7];
  const int*   ridx  = (const int*)d_in[8];
  float* out = (float*)d_out;

  char* ws = (char*)d_ws;
  float*  bias = (float*)ws;                                 //  2 MiB
  bf16_t* q    = (bf16_t*)(ws + (2u << 20));                 // 32 MiB
  bf16_t* k    = (bf16_t*)(ws + (2u << 20) + 33554432u);     // 32 MiB
  bf16_t* v    = (bf16_t*)(ws + (2u << 20) + 67108864u);     // 32 MiB
  const size_t need = 2097152u + 4u * 33554432u;             // 130 MiB

  k_bias<<<256, 256, 0, stream>>>(ridx, rbt, bias);
  k_qkv<<<dim3(256, 12), 256, 0, stream>>>(x, qkvw, qkvb, q, k, v);

  if (ws_size >= need) {
    // fast path: 16384 independent blocks, separate O buffer
    bf16_t* o = (bf16_t*)(ws + (2u << 20) + 100663296u);     // @98 MiB
    k_attn_t<<<16384, 256, 0, stream>>>(q, k, v, o, bias, pew, peb);
    k_proj<<<dim3(256, 4), 256, 0, stream>>>(o, projw, projb, out);
  } else {
    // fallback: per-(w,h) serial, O in place of v
    k_attn_s<<<1024, 256, 0, stream>>>(q, k, v, bias, pew, peb);
    k_proj<<<dim3(256, 4), 256, 0, stream>>>(v, projw, projb, out);
  }
}

// Round 8
// 555.743 us; speedup vs baseline: 2.2613x; 1.0293x over previous
//
#include <hip/hip_runtime.h>

typedef __bf16 bf16_t;
typedef bf16_t bf16x4 __attribute__((ext_vector_type(4)));
typedef bf16_t bf16x8 __attribute__((ext_vector_type(8)));
typedef float floatx4 __attribute__((ext_vector_type(4)));

#define MFMA16(a, b, c) __builtin_amdgcn_mfma_f32_16x16x32_bf16(a, b, c, 0, 0, 0)

__device__ __forceinline__ bf16x4 cvt4(float4 f) {
  bf16x4 o;
  o[0] = (bf16_t)f.x; o[1] = (bf16_t)f.y; o[2] = (bf16_t)f.z; o[3] = (bf16_t)f.w;
  return o;
}

// ---------------------------------------------------------------------------
// K0: bias[h][i][j] = table[rel_index[i*256+j]*8 + h]  (bf16, 1 MiB)
// ---------------------------------------------------------------------------
__global__ __launch_bounds__(256) void k_bias(const int* __restrict__ rel_index,
                                              const float* __restrict__ table,
                                              bf16_t* __restrict__ bias) {
  int ij = blockIdx.x * 256 + threadIdx.x;
  int idx = rel_index[ij];
#pragma unroll
  for (int h = 0; h < 8; ++h)
    bias[h * 65536 + ij] = (bf16_t)table[idx * 8 + h];
}

// ---------------------------------------------------------------------------
// K1: QKV GEMM (unchanged). M=32768, K=512, N=1536.
// ---------------------------------------------------------------------------
#define LDAB 40

__global__ __launch_bounds__(256) void k_qkv(const float* __restrict__ x,
                                             const float* __restrict__ wqkv,
                                             const float* __restrict__ bqkv,
                                             bf16_t* __restrict__ q,
                                             bf16_t* __restrict__ k,
                                             bf16_t* __restrict__ v) {
  __shared__ __align__(16) bf16_t As[128 * LDAB];
  __shared__ __align__(16) bf16_t Bs[128 * LDAB];

  const int tid = threadIdx.x;
  const int m0 = blockIdx.x * 128;
  const int n0 = blockIdx.y * 128;

  const float* aptr[4];
  const float* bptr[4];
#pragma unroll
  for (int i = 0; i < 4; ++i) {
    int id = tid + 256 * i;
    int row = id >> 3;
    int c4 = (id & 7) * 4;
    int r = m0 + row;
    int w = r >> 8, n = r & 255;
    int b = w >> 4, wh = (w >> 2) & 3, ww = w & 3;
    int rh = n >> 4, rw = n & 15;
    int l = wh * 1024 + rh * 64 + ww * 16 + rw;
    aptr[i] = x + (size_t)(b * 4096 + l) * 512 + c4;
    bptr[i] = wqkv + (size_t)(n0 + row) * 512 + c4;
  }

  const int lane = tid & 63, wid = tid >> 6;
  const int wm = (wid >> 1) * 64, wn = (wid & 1) * 64;
  const int lm = lane & 15, lq = lane >> 4;

  floatx4 acc[4][4] = {};

  for (int k0 = 0; k0 < 512; k0 += 32) {
#pragma unroll
    for (int i = 0; i < 4; ++i) {
      int id = tid + 256 * i;
      float4 av = *(const float4*)(aptr[i] + k0);
      float4 bv = *(const float4*)(bptr[i] + k0);
      *(bf16x4*)&As[(id >> 3) * LDAB + (id & 7) * 4] = cvt4(av);
      *(bf16x4*)&Bs[(id >> 3) * LDAB + (id & 7) * 4] = cvt4(bv);
    }
    __syncthreads();
    bf16x8 af[4], bfr[4];
#pragma unroll
    for (int s = 0; s < 4; ++s) {
      af[s]  = *(const bf16x8*)&As[(wm + s * 16 + lm) * LDAB + lq * 8];
      bfr[s] = *(const bf16x8*)&Bs[(wn + s * 16 + lm) * LDAB + lq * 8];
    }
#pragma unroll
    for (int ms = 0; ms < 4; ++ms)
#pragma unroll
      for (int ns = 0; ns < 4; ++ns)
        acc[ms][ns] = MFMA16(af[ms], bfr[ns], acc[ms][ns]);
    __syncthreads();
  }

#pragma unroll
  for (int ms = 0; ms < 4; ++ms) {
#pragma unroll
    for (int ns = 0; ns < 4; ++ns) {
      int col = n0 + wn + ns * 16 + lm;
      int s = col >> 9, rem = col & 511;
      int hh = rem >> 6, d = rem & 63;
      bf16_t* dst = (s == 0) ? q : (s == 1) ? k : v;
      float bc = bqkv[col];
      float scale = (s == 0) ? 0.125f : 1.0f;
#pragma unroll
      for (int r = 0; r < 4; ++r) {
        int row = m0 + wm + ms * 16 + lq * 4 + r;
        int w = row >> 8, n = row & 255;
        float val = (acc[ms][ns][r] + bc) * scale;
        dst[(size_t)((w * 8 + hh) * 256 + n) * 64 + d] = (bf16_t)val;
      }
    }
  }
}

// ---------------------------------------------------------------------------
// K2 v2: one block per (w,h,ti). 2 S-tiles (30 needed rows), conv from
// registers, MFMA-summed softmax (no shuffles/no extra barrier), bias in
// regs, XCD swizzle (bh = blk&1023 -> head pinned per XCD class).
// LDS: vbuf[256][68] bf16 (34816) overlaid by S[30][260] f32 (31200) +
// Pt[16][272] bf16 (8704) = 39904 -> 4 blocks/CU.
// ---------------------------------------------------------------------------
__global__ __launch_bounds__(256, 4) void k_attn_t(const bf16_t* __restrict__ q,
                                                   const bf16_t* __restrict__ k,
                                                   const bf16_t* __restrict__ v,
                                                   bf16_t* __restrict__ o,
                                                   const bf16_t* __restrict__ bias,
                                                   const float* __restrict__ pe_w,
                                                   const float* __restrict__ pe_b) {
  __shared__ __align__(16) char pool[39904];
  __shared__ float pws[15];
  bf16_t* vbuf = (bf16_t*)pool;                // [256][68]  (phase A)
  float*  S    = (float*)pool;                 // [30][260]  (phase B)
  bf16_t* Pt   = (bf16_t*)(pool + 31200);      // [16][272]  (phase B)

  const int blk = blockIdx.x;
  const int bh = blk & 1023, ti = blk >> 10;   // same-bh (and same-head) blocks
  const int h = bh & 7;                        // share an XCD class
  const bf16_t* qb = q + (size_t)bh * 16384;
  const bf16_t* kb = k + (size_t)bh * 16384;
  const bf16_t* vb = v + (size_t)bh * 16384;
  const bf16_t* bb = bias + (size_t)h * 65536;
  const int tid = threadIdx.x, lane = tid & 63, wid = tid >> 6;
  const int lm = lane & 15, lq = lane >> 4;
  const int dcol = wid * 16 + lm;
  const int c = tid;                           // this thread's key column

  if (tid < 15) pws[tid] = pe_w[h * 15 + tid];
  const float peb = pe_b[h];

  // stage v -> LDS (natural layout, pad 68)
#pragma unroll
  for (int it = 0; it < 8; ++it) {
    int id = tid + 256 * it;
    int tok = id >> 3, d8 = (id & 7) * 8;
    *(bf16x8*)&vbuf[tok * 68 + d8] = *(const bf16x8*)(vb + tok * 64 + d8);
  }

  // prefetch K fragments, A (q) fragments, bias rows into registers
  bf16x8 b0[4], b1[4];
#pragma unroll
  for (int ns = 0; ns < 4; ++ns) {
    int tk = wid * 64 + ns * 16 + lm;
    b0[ns] = *(const bf16x8*)(kb + (size_t)tk * 64 + lq * 8);
    b1[ns] = *(const bf16x8*)(kb + (size_t)tk * 64 + 32 + lq * 8);
  }
  const int base = ti * 16 - 7;
  bf16x8 a0[2], a1[2];
#pragma unroll
  for (int t = 0; t < 2; ++t) {
    int qrow = base + t * 16 + lm;
    qrow = qrow < 0 ? 0 : (qrow > 255 ? 255 : qrow);
    a0[t] = *(const bf16x8*)(qb + (size_t)qrow * 64 + lq * 8);
    a1[t] = *(const bf16x8*)(qb + (size_t)qrow * 64 + 32 + lq * 8);
  }
  bf16_t biasreg[16];
#pragma unroll
  for (int r = 0; r < 16; ++r)
    biasreg[r] = bb[(size_t)(ti * 16 + r) * 256 + c];

  __syncthreads();                             // [A] vbuf ready

  // V B-fragments to registers (wave's d = dcol, all 256 keys)
  bf16x8 vf[8];
#pragma unroll
  for (int kt = 0; kt < 8; ++kt)
#pragma unroll
    for (int j = 0; j < 8; ++j)
      vf[kt][j] = vbuf[(kt * 32 + lq * 8 + j) * 68 + dcol];

  __syncthreads();                             // [B] vbuf dead; S region live

  // zero conv halo rows at window edges (never written by MFMA stores below)
  if (ti == 0)
#pragma unroll
    for (int r = 0; r < 7; ++r) S[r * 260 + tid] = 0.f;
  if (ti == 15)
#pragma unroll
    for (int r = 23; r < 30; ++r) S[r * 260 + tid] = 0.f;

  // S rows base..base+31 (local 0..31, keep 0..29), guarded stores
#pragma unroll
  for (int t = 0; t < 2; ++t) {
#pragma unroll
    for (int ns = 0; ns < 4; ++ns) {
      floatx4 acc = {0.f, 0.f, 0.f, 0.f};
      acc = MFMA16(a0[t], b0[ns], acc);
      acc = MFMA16(a1[t], b1[ns], acc);
      int col = wid * 64 + ns * 16 + lm;
#pragma unroll
      for (int r = 0; r < 4; ++r) {
        int lr = t * 16 + lq * 4 + r;
        bool ok = (lr < 30) && !(ti == 0 && lr < 7) && !(ti == 15 && lr > 22);
        if (ok) S[lr * 260 + col] = acc[r];
      }
    }
  }
  __syncthreads();                             // [C] S ready

  // conv from registers: 30 column values, 16 rows x 15 taps
  float sreg[30];
#pragma unroll
  for (int i = 0; i < 30; ++i) sreg[i] = S[i * 260 + c];
  float p[16];
#pragma unroll
  for (int r = 0; r < 16; ++r) {
    float acc = sreg[r + 7] + peb + (float)biasreg[r];
#pragma unroll
    for (int j = 0; j < 15; ++j)
      acc += sreg[r + j] * pws[j];
    p[r] = __expf(fminf(fmaxf(acc, -60.f), 60.f));  // unnormalized
  }
#pragma unroll
  for (int r = 0; r < 16; ++r)
    Pt[r * 272 + c] = (bf16_t)p[r];
  __syncthreads();                             // [D] Pt ready

  // PV + row-sum via MFMA (ones B-fragment); O = O'/L
  bf16x8 vones;
#pragma unroll
  for (int j = 0; j < 8; ++j) vones[j] = (bf16_t)1.0f;
  floatx4 oacc = {0.f, 0.f, 0.f, 0.f};
  floatx4 lacc = {0.f, 0.f, 0.f, 0.f};
#pragma unroll
  for (int kt = 0; kt < 8; ++kt) {
    bf16x8 a = *(const bf16x8*)&Pt[lm * 272 + kt * 32 + lq * 8];
    oacc = MFMA16(a, vf[kt], oacc);
    lacc = MFMA16(a, vones, lacc);
  }
  bf16_t* ob = o + (size_t)bh * 16384;
#pragma unroll
  for (int r = 0; r < 4; ++r)
    ob[(size_t)(ti * 16 + lq * 4 + r) * 64 + dcol] = (bf16_t)(oacc[r] / lacc[r]);
}

// ---------------------------------------------------------------------------
// K2 fallback (small ws): per-(w,h) serial, O in place of v. Unchanged except
// bf16 bias.
// ---------------------------------------------------------------------------
__global__ __launch_bounds__(256) void k_attn_s(const bf16_t* __restrict__ q,
                                                const bf16_t* __restrict__ k,
                                                bf16_t* __restrict__ v_io,
                                                const bf16_t* __restrict__ bias,
                                                const float* __restrict__ pe_w,
                                                const float* __restrict__ pe_b) {
  __shared__ __align__(16) char pool[58368];
  __shared__ float redB[4][16];
  __shared__ float pws[15];
  bf16_t* vbuf = (bf16_t*)pool;
  float*  ring = (float*)pool;                 // [3][16][260]
  bf16_t* Pt   = (bf16_t*)(pool + 49920);      // [16][264]

  const int bh = blockIdx.x;
  const int h = bh & 7;
  const bf16_t* qb = q + (size_t)bh * 16384;
  const bf16_t* kb = k + (size_t)bh * 16384;
  bf16_t* vb = v_io + (size_t)bh * 16384;
  const bf16_t* bb = bias + (size_t)h * 65536;
  const int tid = threadIdx.x, lane = tid & 63, wid = tid >> 6;
  const int lm = lane & 15, lq = lane >> 4;
  const int dcol = wid * 16 + lm;

  if (tid < 15) pws[tid] = pe_w[h * 15 + tid];
  const float peb = pe_b[h];

#pragma unroll
  for (int it = 0; it < 8; ++it) {
    int id = tid + 256 * it;
    int tok = id >> 3, d8 = (id & 7) * 8;
    *(bf16x8*)&vbuf[tok * 68 + d8] = *(const bf16x8*)(vb + tok * 64 + d8);
  }
  __syncthreads();
  bf16x8 vf[8];
#pragma unroll
  for (int kt = 0; kt < 8; ++kt)
#pragma unroll
    for (int j = 0; j < 8; ++j)
      vf[kt][j] = vbuf[(kt * 32 + lq * 8 + j) * 68 + dcol];
  __syncthreads();

  bf16x8 b0[4], b1[4];
#pragma unroll
  for (int ns = 0; ns < 4; ++ns) {
    int tk = wid * 64 + ns * 16 + lm;
    b0[ns] = *(const bf16x8*)(kb + (size_t)tk * 64 + lq * 8);
    b1[ns] = *(const bf16x8*)(kb + (size_t)tk * 64 + 32 + lq * 8);
  }

  auto computeS = [&](int ti2) {
    if (ti2 >= 16) return;
    int slot = ti2 % 3;
    int tq = ti2 * 16 + lm;
    bf16x8 a0 = *(const bf16x8*)(qb + (size_t)tq * 64 + lq * 8);
    bf16x8 a1 = *(const bf16x8*)(qb + (size_t)tq * 64 + 32 + lq * 8);
#pragma unroll
    for (int ns = 0; ns < 4; ++ns) {
      floatx4 acc = {0.f, 0.f, 0.f, 0.f};
      acc = MFMA16(a0, b0[ns], acc);
      acc = MFMA16(a1, b1[ns], acc);
      int col = wid * 64 + ns * 16 + lm;
#pragma unroll
      for (int r = 0; r < 4; ++r)
        ring[(slot * 16 + lq * 4 + r) * 260 + col] = acc[r];
    }
  };

  computeS(0);
  const int c = tid;
  for (int ti = 0; ti < 16; ++ti) {
    computeS(ti + 1);
    __syncthreads();

    float p[16];
#pragma unroll
    for (int r = 0; r < 16; ++r) {
      int R = ti * 16 + r;
      float acc = ring[((R >> 4) % 3 * 16 + (R & 15)) * 260 + c] + peb +
                  (float)bb[(size_t)R * 256 + c];
#pragma unroll
      for (int j = 0; j < 15; ++j) {
        int R2 = R + j - 7;
        if (R2 >= 0 && R2 < 256)
          acc += ring[((R2 >> 4) % 3 * 16 + (R2 & 15)) * 260 + c] * pws[j];
      }
      p[r] = __expf(fminf(fmaxf(acc, -60.f), 60.f));
    }
#pragma unroll
    for (int r = 0; r < 16; ++r) {
      float s = p[r];
      for (int off = 32; off; off >>= 1) s += __shfl_xor(s, off);
      if (lane == 0) redB[wid][r] = s;
    }
    __syncthreads();
#pragma unroll
    for (int r = 0; r < 16; ++r) {
      float inv = 1.0f / (redB[0][r] + redB[1][r] + redB[2][r] + redB[3][r]);
      Pt[r * 264 + c] = (bf16_t)(p[r] * inv);
    }
    __syncthreads();

    floatx4 oacc = {0.f, 0.f, 0.f, 0.f};
#pragma unroll
    for (int kt = 0; kt < 8; ++kt) {
      bf16x8 a = *(const bf16x8*)&Pt[lm * 264 + kt * 32 + lq * 8];
      oacc = MFMA16(a, vf[kt], oacc);
    }
#pragma unroll
    for (int r = 0; r < 4; ++r)
      vb[(size_t)(ti * 16 + lq * 4 + r) * 64 + dcol] = (bf16_t)oacc[r];
  }
}

// ---------------------------------------------------------------------------
// K5: proj GEMM (unchanged). A in O-layout [w][h][n][d]; fp32 output.
// ---------------------------------------------------------------------------
__global__ __launch_bounds__(256) void k_proj(const bf16_t* __restrict__ A,
                                              const float* __restrict__ Wp,
                                              const float* __restrict__ bp,
                                              float* __restrict__ out) {
  __shared__ __align__(16) bf16_t As[128 * LDAB];
  __shared__ __align__(16) bf16_t Bs[128 * LDAB];

  const int tid = threadIdx.x;
  const int m0 = blockIdx.x * 128;
  const int n0 = blockIdx.y * 128;
  const int lane = tid & 63, wid = tid >> 6;
  const int wm = (wid >> 1) * 64, wn = (wid & 1) * 64;
  const int lm = lane & 15, lq = lane >> 4;

  size_t abase[2];
#pragma unroll
  for (int i = 0; i < 2; ++i) {
    int id = tid + 256 * i;
    int r = m0 + (id >> 2);
    int w = r >> 8, n = r & 255;
    abase[i] = (size_t)w * 131072 + (size_t)n * 64 + (id & 3) * 8;
  }
  const float* bptr[4];
#pragma unroll
  for (int i = 0; i < 4; ++i) {
    int id = tid + 256 * i;
    bptr[i] = Wp + (size_t)(n0 + (id >> 3)) * 512 + (id & 7) * 4;
  }

  floatx4 acc[4][4] = {};

  for (int k0 = 0; k0 < 512; k0 += 32) {
#pragma unroll
    for (int i = 0; i < 2; ++i) {
      int id = tid + 256 * i;
      bf16x8 av = *(const bf16x8*)(A + abase[i] + (k0 >> 6) * 16384 + (k0 & 63));
      *(bf16x8*)&As[(id >> 2) * LDAB + (id & 3) * 8] = av;
    }
#pragma unroll
    for (int i = 0; i < 4; ++i) {
      int id = tid + 256 * i;
      float4 bv = *(const float4*)(bptr[i] + k0);
      *(bf16x4*)&Bs[(id >> 3) * LDAB + (id & 7) * 4] = cvt4(bv);
    }
    __syncthreads();
    bf16x8 af[4], bfr[4];
#pragma unroll
    for (int s = 0; s < 4; ++s) {
      af[s]  = *(const bf16x8*)&As[(wm + s * 16 + lm) * LDAB + lq * 8];
      bfr[s] = *(const bf16x8*)&Bs[(wn + s * 16 + lm) * LDAB + lq * 8];
    }
#pragma unroll
    for (int ms = 0; ms < 4; ++ms)
#pragma unroll
      for (int ns = 0; ns < 4; ++ns)
        acc[ms][ns] = MFMA16(af[ms], bfr[ns], acc[ms][ns]);
    __syncthreads();
  }

#pragma unroll
  for (int ms = 0; ms < 4; ++ms) {
#pragma unroll
    for (int r = 0; r < 4; ++r) {
      int row = m0 + wm + ms * 16 + lq * 4 + r;
      int w = row >> 8, n = row & 255;
      int b = w >> 4, wh = (w >> 2) & 3, ww = w & 3;
      int rh = n >> 4, rw = n & 15;
      int l = wh * 1024 + rh * 64 + ww * 16 + rw;
      size_t obase = (size_t)(b * 4096 + l) * 512;
#pragma unroll
      for (int ns = 0; ns < 4; ++ns) {
        int col = n0 + wn + ns * 16 + lm;
        out[obase + col] = acc[ms][ns][r] + bp[col];
      }
    }
  }
}

// ---------------------------------------------------------------------------
extern "C" void kernel_launch(void* const* d_in, const int* in_sizes, int n_in,
                              void* d_out, int out_size, void* d_ws, size_t ws_size,
                              hipStream_t stream) {
  const float* x     = (const float*)d_in[0];
  const float* qkvw  = (const float*)d_in[1];
  const float* qkvb  = (const float*)d_in[2];
  const float* projw = (const float*)d_in[3];
  const float* projb = (const float*)d_in[4];
  const float* rbt   = (const float*)d_in[5];
  const float* pew   = (const float*)d_in[6];
  const float* peb   = (const float*)d_in[7];
  const int*   ridx  = (const int*)d_in[8];
  float* out = (float*)d_out;

  char* ws = (char*)d_ws;
  bf16_t* bias = (bf16_t*)ws;                                //  1 MiB bf16
  bf16_t* q    = (bf16_t*)(ws + (2u << 20));                 // 32 MiB
  bf16_t* k    = (bf16_t*)(ws + (2u << 20) + 33554432u);     // 32 MiB
  bf16_t* v    = (bf16_t*)(ws + (2u << 20) + 67108864u);     // 32 MiB
  const size_t need = 2097152u + 4u * 33554432u;             // 130 MiB

  k_bias<<<256, 256, 0, stream>>>(ridx, rbt, bias);
  k_qkv<<<dim3(256, 12), 256, 0, stream>>>(x, qkvw, qkvb, q, k, v);

  if (ws_size >= need) {
    bf16_t* o = (bf16_t*)(ws + (2u << 20) + 100663296u);     // @98 MiB
    k_attn_t<<<16384, 256, 0, stream>>>(q, k, v, o, bias, pew, peb);
    k_proj<<<dim3(256, 4), 256, 0, stream>>>(o, projw, projb, out);
  } else {
    k_attn_s<<<1024, 256, 0, stream>>>(q, k, v, bias, pew, peb);
    k_proj<<<dim3(256, 4), 256, 0, stream>>>(v, projw, projb, out);
  }
}